// Round 9
// baseline (843.258 us; speedup 1.0000x reference)
//
#include <hip/hip_runtime.h>
#include <hip/hip_bf16.h>

// ---------------------------------------------------------------------------
// 4-dispatch pipeline:
//  1) conv_hist : blocks [0,128) = per-partition LDS hist of dst buckets ->
//                 cnt128[bucket][part] (no atomics, no memset);
//                 blocks [128,..) = fp32->bf16 conv of feature+W.
//  2) scan128   : one block: bucket_off + per-(bucket,partition) cursors.
//  3) p_scatter : partition (dst,src) pairs into bucket regions, LDS cursors
//                 only (128B runs/bucket, round-5 proven write locality).
//  4) bucket_mm : one block per 128-node bucket. Waves stream UNSORTED pairs,
//                 accumulate rows into a 128x128 fp32 LDS tile via ds_add_f32
//                 (independent iterations - no per-node chains, no CSR),
//                 then MFMA 16x16x32_bf16 projection + bias + fp32 store.
// ---------------------------------------------------------------------------

#define BKT_SHIFT 7                 // 128 nodes per bucket
#define MAX_BKT   512               // >= ceil(50000/128)+1
#define NPART     128               // partition blocks (write-locality sweet spot)
#define HT_PAR    132               // tile row stride (dwords): x[0,64) y[64,128) pad 4

typedef __attribute__((ext_vector_type(8))) short short8;
typedef __attribute__((ext_vector_type(4))) float float4v;

__device__ __forceinline__ unsigned short f2bf_rne(float f) {
    unsigned int u = __float_as_uint(f);
    u += 0x7FFFu + ((u >> 16) & 1u);
    return (unsigned short)(u >> 16);
}

// --- 1) fused conv + per-partition hist ---
__global__ __launch_bounds__(256) void conv_hist_kernel(
    const float* __restrict__ feat, const float* __restrict__ W,
    unsigned short* __restrict__ out_bf, long nf, long nw,
    const int* __restrict__ dst, int* __restrict__ cnt128,
    int n_edges, int nb, int chunk)
{
    if ((int)blockIdx.x < NPART) {
        __shared__ int lcnt[MAX_BKT];
        int tid = threadIdx.x;
        int p   = blockIdx.x;
        int e0  = p * chunk;
        int e1  = min(e0 + chunk, n_edges);
        for (int i = tid; i < nb; i += 256) lcnt[i] = 0;
        __syncthreads();
        for (int e = e0 + tid; e < e1; e += 256)
            atomicAdd(&lcnt[dst[e] >> BKT_SHIFT], 1);
        __syncthreads();
        for (int i = tid; i < nb; i += 256)
            cnt128[i * NPART + p] = lcnt[i];     // bucket-major, no atomics
    } else {
        long i4 = ((long)(blockIdx.x - NPART) * 256 + threadIdx.x) * 4;
        if (i4 >= nf + nw) return;               // nf, nw multiples of 4
        const float* srcp = (i4 < nf) ? (feat + i4) : (W + (i4 - nf));
        float4 v = *(const float4*)srcp;
        ushort4 o;
        o.x = f2bf_rne(v.x); o.y = f2bf_rne(v.y);
        o.z = f2bf_rne(v.z); o.w = f2bf_rne(v.w);
        *(ushort4*)(out_bf + i4) = o;
    }
}

// --- 2) scan128: totals -> bucket_off; per-(bucket,part) cursors ---
__global__ __launch_bounds__(1024) void scan128_kernel(
    const int* __restrict__ cnt128, int* __restrict__ cursor128,
    int* __restrict__ bucket_off, int nb)
{
    __shared__ int tot[MAX_BKT];
    __shared__ int toff[MAX_BKT + 1];
    int tid  = threadIdx.x;
    int lane = tid & 63;
    int wid  = tid >> 6;

    for (int j = wid; j < nb; j += 16) {
        int2 v = *(const int2*)(cnt128 + j * NPART + 2 * lane);
        int s = v.x + v.y;
        #pragma unroll
        for (int off = 1; off < 64; off <<= 1) s += __shfl_xor(s, off, 64);
        if (lane == 0) tot[j] = s;
    }
    __syncthreads();
    if (wid == 0) {
        const int PER = 8;
        int base = lane * PER;
        int v[PER];
        int sum = 0;
        #pragma unroll
        for (int k = 0; k < PER; k++) {
            v[k] = (base + k < nb) ? tot[base + k] : 0;
            sum += v[k];
        }
        int x = sum;
        #pragma unroll
        for (int off = 1; off < 64; off <<= 1) {
            int y = __shfl_up(x, off, 64);
            if (lane >= off) x += y;
        }
        int run = x - sum;
        #pragma unroll
        for (int k = 0; k < PER; k++) {
            int idx = base + k;
            if (idx <= nb) { toff[idx] = run; bucket_off[idx] = run; }
            run += v[k];
        }
    }
    __syncthreads();
    for (int j = wid; j < nb; j += 16) {
        int2 v = *(const int2*)(cnt128 + j * NPART + 2 * lane);
        int s = v.x + v.y;
        int x = s;
        #pragma unroll
        for (int off = 1; off < 64; off <<= 1) {
            int y = __shfl_up(x, off, 64);
            if (lane >= off) x += y;
        }
        int e0 = x - s + toff[j];
        int2 o;
        o.x = e0;
        o.y = e0 + v.x;
        *(int2*)(cursor128 + j * NPART + 2 * lane) = o;
    }
}

// --- 3) p_scatter: partition edges into bucket regions (no global atomics) ---
__global__ __launch_bounds__(256) void p_scatter_kernel(
    const int* __restrict__ src, const int* __restrict__ dst,
    const int* __restrict__ cursor128, int2* __restrict__ pairs,
    int n_edges, int nb, int chunk)
{
    __shared__ int lcur[MAX_BKT];
    int tid = threadIdx.x;
    int p   = blockIdx.x;
    int e0  = p * chunk;
    int e1  = min(e0 + chunk, n_edges);

    for (int i = tid; i < nb; i += 256) lcur[i] = cursor128[i * NPART + p];
    __syncthreads();
    for (int e = e0 + tid; e < e1; e += 256) {
        int d = dst[e];
        int s = src[e];
        int pos = atomicAdd(&lcur[d >> BKT_SHIFT], 1);   // LDS atomic only
        pairs[pos] = make_int2(d, s);
    }
}

// --- 4) bucket_mm helpers ---
__device__ __forceinline__ void acc_edge(
    float* tile, int d, int s, int lane,
    const float* __restrict__ feat_f32,
    const unsigned short* __restrict__ feat_bf, int use_bf16)
{
    float fx, fy;
    if (use_bf16) {
        unsigned int u = *(const unsigned int*)(feat_bf + (size_t)s * 128 + 2 * lane);
        fx = __uint_as_float(u << 16);
        fy = __uint_as_float(u & 0xFFFF0000u);
    } else {
        float2 v = ((const float2*)(feat_f32 + (size_t)s * 128))[lane];
        fx = v.x; fy = v.y;
    }
    // split layout: col 2*lane -> [d][lane], col 2*lane+1 -> [d][64+lane]
    // addr = d*132 + lane (+64): 64 lanes over 32 banks 2-way = free (m136)
    atomicAdd(&tile[d * HT_PAR + lane], fx);
    atomicAdd(&tile[d * HT_PAR + 64 + lane], fy);
}

// --- 4) bucket_mm: LDS-atomic accumulate over unsorted pairs + MFMA ---
__global__ __launch_bounds__(512, 4) void bucket_mm_kernel(
    const float* __restrict__ feat_f32,
    const unsigned short* __restrict__ feat_bf, int use_bf16,
    const int2* __restrict__ pairs, const int* __restrict__ bucket_off,
    const unsigned short* __restrict__ w_bf, const float* __restrict__ bias,
    float* __restrict__ out, int n_nodes)
{
    __shared__ float tile[128 * HT_PAR];    // 67584 B -> 2 blocks/CU

    int tid  = threadIdx.x;
    int lane = tid & 63;
    int w    = tid >> 6;                    // wave 0..7
    int b    = blockIdx.x;
    int node_base = b << BKT_SHIFT;

    // zero the tile (128*132/4 = 4224 float4)
    for (int i4 = tid; i4 < 128 * HT_PAR / 4; i4 += 512)
        *(float4*)(tile + i4 * 4) = make_float4(0.f, 0.f, 0.f, 0.f);

    int bstart = bucket_off[b];
    int bend   = bucket_off[b + 1];
    int cnt    = bend - bstart;
    int chunk  = (cnt + 7) >> 3;            // contiguous slice per wave
    int e      = bstart + w * chunk;
    int myend  = min(e + chunk, bend);

    __syncthreads();

    // ---- accumulate phase: independent iterations, no chains ----
    while (e + 64 <= myend) {
        int2 pr = pairs[e + lane];          // coalesced 512B burst
        #pragma unroll 4
        for (int i = 0; i < 64; ++i) {
            int d = __shfl(pr.x, i) - node_base;   // readlane broadcast
            int s = __shfl(pr.y, i);
            acc_edge(tile, d, s, lane, feat_f32, feat_bf, use_bf16);
        }
        e += 64;
    }
    if (e < myend) {
        int n = myend - e;
        int2 pr = (lane < n) ? pairs[e + lane] : make_int2(node_base, 0);
        for (int i = 0; i < n; ++i) {
            int d = __shfl(pr.x, i) - node_base;
            int s = __shfl(pr.y, i);
            acc_edge(tile, d, s, lane, feat_f32, feat_bf, use_bf16);
        }
    }

    __syncthreads();

    // ---- MFMA projection: wave w handles rows w*16..w*16+15 ----
    // A[m=lane&15][k=quad*8+j]: k even from x-half, k odd from y-half.
    int m = lane & 15;
    int q = lane >> 4;
    const float* rowp = tile + (w * 16 + m) * HT_PAR;

    short8 afrag[4];
    #pragma unroll
    for (int kk = 0; kk < 4; ++kk) {
        float4 xa = *(const float4*)(rowp + kk * 16 + q * 4);        // 16B aligned
        float4 ya = *(const float4*)(rowp + 64 + kk * 16 + q * 4);
        short8 a;
        a[0] = (short)f2bf_rne(xa.x); a[1] = (short)f2bf_rne(ya.x);
        a[2] = (short)f2bf_rne(xa.y); a[3] = (short)f2bf_rne(ya.y);
        a[4] = (short)f2bf_rne(xa.z); a[5] = (short)f2bf_rne(ya.z);
        a[6] = (short)f2bf_rne(xa.w); a[7] = (short)f2bf_rne(ya.w);
        afrag[kk] = a;
    }

    for (int t = 0; t < 8; ++t) {
        float4v acc = {0.f, 0.f, 0.f, 0.f};
        #pragma unroll
        for (int kk = 0; kk < 4; ++kk) {
            short8 bfrag = *(const short8*)(w_bf + (size_t)(t * 16 + m) * 128 + kk * 32 + q * 8);
            acc = __builtin_amdgcn_mfma_f32_16x16x32_bf16(afrag[kk], bfrag, acc, 0, 0, 0);
        }
        float bv = bias[t * 16 + m];
        #pragma unroll
        for (int r = 0; r < 4; ++r) {
            int row = node_base + w * 16 + q * 4 + r;   // D: col=lane&15, row=q*4+r
            if (row < n_nodes)
                out[(size_t)row * 128 + t * 16 + m] = acc[r] + bv;
        }
    }
}

extern "C" void kernel_launch(void* const* d_in, const int* in_sizes, int n_in,
                              void* d_out, int out_size, void* d_ws, size_t ws_size,
                              hipStream_t stream) {
    const float* feature = (const float*)d_in[0];
    const int*   src     = (const int*)d_in[1];
    const int*   dst     = (const int*)d_in[2];
    const float* W       = (const float*)d_in[3];
    const float* b       = (const float*)d_in[4];

    const int D  = 128;
    int n_nodes  = in_sizes[0] / D;
    int n_edges  = in_sizes[1];
    int nb       = (n_nodes + 127) >> BKT_SHIFT;   // 391

    float* out = (float*)d_out;

    long nf = (long)n_nodes * D;      // feature elems (mult of 4)
    long nw = (long)D * D;            // W elems

    // ws: [feature_bf nf?] [w_bf nw] [pairs E int2]
    //     [cnt128 512*128] [cursor128 512*128] [bucket_off 513]
    size_t tail_bytes = (size_t)n_edges * 8 +
                        (size_t)(2 * MAX_BKT * NPART + MAX_BKT + 1) * 4;
    size_t need_full  = (size_t)(nf + nw) * 2 + tail_bytes;
    int use_bf16 = (ws_size >= need_full) ? 1 : 0;   // constant across calls

    unsigned short* bf_base    = (unsigned short*)d_ws;
    long            nf_eff     = use_bf16 ? nf : 0;
    unsigned short* feature_bf = bf_base;            // valid only if use_bf16
    unsigned short* w_bf       = bf_base + nf_eff;
    int2* pairs        = (int2*)(bf_base + nf_eff + nw);
    int* cnt128        = (int*)(pairs + n_edges);
    int* cursor128     = cnt128 + MAX_BKT * NPART;
    int* bucket_off    = cursor128 + MAX_BKT * NPART;

    int chunk = (n_edges + NPART - 1) / NPART;   // 6250

    // 1) conv + hist
    {
        long conv_blocks = ((nf_eff + nw) / 4 + 255) / 256;
        int grid = NPART + (int)conv_blocks;
        conv_hist_kernel<<<grid, 256, 0, stream>>>(
            feature, W, bf_base, nf_eff, nw, dst, cnt128, n_edges, nb, chunk);
    }

    // 2) scan
    scan128_kernel<<<1, 1024, 0, stream>>>(cnt128, cursor128, bucket_off, nb);

    // 3) scatter into bucket regions
    p_scatter_kernel<<<NPART, 256, 0, stream>>>(src, dst, cursor128, pairs,
                                                n_edges, nb, chunk);

    // 4) bucket-resident accumulate + MFMA projection
    bucket_mm_kernel<<<nb, 512, 0, stream>>>(
        feature, feature_bf, use_bf16, pairs, bucket_off, w_bf, b, out, n_nodes);
}

// Round 10
// 185.636 us; speedup vs baseline: 4.5425x; 4.5425x over previous
//
#include <hip/hip_runtime.h>
#include <hip/hip_bf16.h>

// ---------------------------------------------------------------------------
// 4-dispatch pipeline (round-8 base, proven 187.7us, minus scan dispatch):
//  1) conv_hist      : blocks [0,128) = per-partition LDS hist of dst buckets
//                      -> cnt128[bucket][part]; rest = fp32->bf16 conv.
//  2) p_scatter_scan : 128 blocks; each REDUNDANTLY recomputes the bucket
//                      scan from cnt128 (parallel, L2-resident) -> own LDS
//                      cursors; block 0 writes bucket_off; then scatters
//                      (dst,src) pairs into bucket regions (128B runs).
//  3) local_csr      : per-bucket exact CSR via LDS hist+scan (proven).
//  4) gather_mm      : 16 waves = 16 nodes, one wave per node, UNROLL-8
//                      gather (8 rows in flight), MFMA projection (proven).
// ---------------------------------------------------------------------------

#define BKT_SHIFT 7                 // 128 nodes per bucket
#define MAX_BKT   512               // >= ceil(50000/128)+1
#define NPART     128               // partition blocks (write-locality sweet spot)

typedef __attribute__((ext_vector_type(8))) short short8;
typedef __attribute__((ext_vector_type(4))) float float4v;

__device__ __forceinline__ unsigned short f2bf_rne(float f) {
    unsigned int u = __float_as_uint(f);
    u += 0x7FFFu + ((u >> 16) & 1u);
    return (unsigned short)(u >> 16);
}

// --- 1) fused conv + per-partition hist ---
__global__ __launch_bounds__(256) void conv_hist_kernel(
    const float* __restrict__ feat, const float* __restrict__ W,
    unsigned short* __restrict__ out_bf, long nf, long nw,
    const int* __restrict__ dst, int* __restrict__ cnt128,
    int n_edges, int nb, int chunk)
{
    if ((int)blockIdx.x < NPART) {
        __shared__ int lcnt[MAX_BKT];
        int tid = threadIdx.x;
        int p   = blockIdx.x;
        int e0  = p * chunk;
        int e1  = min(e0 + chunk, n_edges);
        for (int i = tid; i < nb; i += 256) lcnt[i] = 0;
        __syncthreads();
        for (int e = e0 + tid; e < e1; e += 256)
            atomicAdd(&lcnt[dst[e] >> BKT_SHIFT], 1);
        __syncthreads();
        for (int i = tid; i < nb; i += 256)
            cnt128[i * NPART + p] = lcnt[i];     // bucket-major, no atomics
    } else {
        long i4 = ((long)(blockIdx.x - NPART) * 256 + threadIdx.x) * 4;
        if (i4 >= nf + nw) return;               // nf, nw multiples of 4
        const float* srcp = (i4 < nf) ? (feat + i4) : (W + (i4 - nf));
        float4 v = *(const float4*)srcp;
        ushort4 o;
        o.x = f2bf_rne(v.x); o.y = f2bf_rne(v.y);
        o.z = f2bf_rne(v.z); o.w = f2bf_rne(v.w);
        *(ushort4*)(out_bf + i4) = o;
    }
}

// --- 2) p_scatter_scan: redundant per-block scan + scatter (no global atomics)
__global__ __launch_bounds__(512) void p_scatter_scan_kernel(
    const int* __restrict__ src, const int* __restrict__ dst,
    const int* __restrict__ cnt128, int2* __restrict__ pairs,
    int* __restrict__ bucket_off, int n_edges, int nb, int chunk)
{
    __shared__ int tot[MAX_BKT];        // bucket totals
    __shared__ int pre[MAX_BKT];        // this block's partition prefix
    __shared__ int toff[MAX_BKT + 1];   // exclusive scan of totals
    __shared__ int lcur[MAX_BKT];       // scatter cursors
    int tid  = threadIdx.x;
    int lane = tid & 63;
    int wid  = tid >> 6;                // 8 waves
    int p    = blockIdx.x;

    // Per-bucket: inclusive shfl-scan over the 128 partition counts
    // (2 per lane) -> this block's prefix (partitions < p) and the total.
    for (int j = wid; j < nb; j += 8) {
        int2 v = *(const int2*)(cnt128 + j * NPART + 2 * lane);
        int s = v.x + v.y;
        int x = s;
        #pragma unroll
        for (int off = 1; off < 64; off <<= 1) {
            int y = __shfl_up(x, off, 64);
            if (lane >= off) x += y;
        }
        int e0 = x - s;                          // excl. prefix before part 2*lane
        int ex = __shfl(e0, p >> 1);
        int vx = __shfl(v.x, p >> 1);
        if (lane == 0)  pre[j] = ex + ((p & 1) ? vx : 0);
        if (lane == 63) tot[j] = x;
    }
    __syncthreads();
    // Wave 0: exclusive scan of bucket totals (8 per lane)
    if (wid == 0) {
        const int PER = 8;
        int base = lane * PER;
        int v[PER];
        int sum = 0;
        #pragma unroll
        for (int k = 0; k < PER; k++) {
            v[k] = (base + k < nb) ? tot[base + k] : 0;
            sum += v[k];
        }
        int x = sum;
        #pragma unroll
        for (int off = 1; off < 64; off <<= 1) {
            int y = __shfl_up(x, off, 64);
            if (lane >= off) x += y;
        }
        int run = x - sum;
        #pragma unroll
        for (int k = 0; k < PER; k++) {
            int idx = base + k;
            if (idx <= nb) toff[idx] = run;
            run += v[k];
        }
    }
    __syncthreads();
    for (int i = tid; i < nb; i += 512) lcur[i] = toff[i] + pre[i];
    if (p == 0)
        for (int i = tid; i <= nb; i += 512) bucket_off[i] = toff[i];
    __syncthreads();

    int e0b = p * chunk;
    int e1  = min(e0b + chunk, n_edges);
    for (int e = e0b + tid; e < e1; e += 512) {
        int d = dst[e];
        int s = src[e];
        int pos = atomicAdd(&lcur[d >> BKT_SHIFT], 1);   // LDS atomic only
        pairs[pos] = make_int2(d, s);
    }
}

// --- 3) local_csr: per bucket (128 nodes) exact CSR via LDS hist + scan ---
__global__ __launch_bounds__(256) void local_csr_kernel(
    const int2* __restrict__ pairs, const int* __restrict__ bucket_off,
    int* __restrict__ offs, int* __restrict__ src_sorted,
    int n_nodes, int n_edges)
{
    __shared__ int hist[128];
    __shared__ int excl[128];
    __shared__ int curs[128];
    int b   = blockIdx.x;
    int tid = threadIdx.x;
    int node_base = b << BKT_SHIFT;
    int bstart = bucket_off[b];
    int bend   = bucket_off[b + 1];

    if (tid < 128) hist[tid] = 0;
    __syncthreads();
    for (int i = bstart + tid; i < bend; i += 256)
        atomicAdd(&hist[pairs[i].x - node_base], 1);
    __syncthreads();
    if (tid < 64) {
        int v0 = hist[2 * tid];
        int v1 = hist[2 * tid + 1];
        int s  = v0 + v1;
        int x  = s;
        #pragma unroll
        for (int off = 1; off < 64; off <<= 1) {
            int y = __shfl_up(x, off, 64);
            if (tid >= off) x += y;
        }
        int e0 = x - s;
        excl[2 * tid]     = e0;
        excl[2 * tid + 1] = e0 + v0;
    }
    __syncthreads();
    if (tid < 128) {
        int pos = bstart + excl[tid];
        int node = node_base + tid;
        if (node < n_nodes) offs[node] = pos;
        curs[tid] = pos;
    }
    __syncthreads();
    for (int i = bstart + tid; i < bend; i += 256) {
        int2 p = pairs[i];
        int pos = atomicAdd(&curs[p.x - node_base], 1);
        src_sorted[pos] = p.y;
    }
    if (b == 0 && tid == 0) offs[n_nodes] = n_edges;
}

// --- 4) FUSED gather + MFMA projection, unroll-8 gather ---
#define HT_STRIDE 136

__global__ __launch_bounds__(1024, 8) void gcn_gather_mm_kernel(
    const float* __restrict__ feat_f32,
    const unsigned short* __restrict__ feat_bf, int use_bf16,
    const int* __restrict__ offs, const int* __restrict__ src_sorted,
    const unsigned short* __restrict__ w_bf, const float* __restrict__ bias,
    float* __restrict__ out, int n_nodes)
{
    __shared__ unsigned short htile[16 * HT_STRIDE];   // 4352 B

    int tid   = threadIdx.x;
    int lane  = tid & 63;
    int w     = tid >> 6;          // wave id 0..15 == local row
    int node0 = blockIdx.x * 16;
    int node  = node0 + w;

    float accx = 0.f, accy = 0.f;
    if (node < n_nodes) {
        int beg = offs[node];
        int end = offs[node + 1];
        int i = beg;
        if (use_bf16) {
            // unroll 8: 8 independent row loads in flight
            for (; i + 7 < end; i += 8) {
                int s0 = src_sorted[i],     s1 = src_sorted[i + 1];
                int s2 = src_sorted[i + 2], s3 = src_sorted[i + 3];
                int s4 = src_sorted[i + 4], s5 = src_sorted[i + 5];
                int s6 = src_sorted[i + 6], s7 = src_sorted[i + 7];
                unsigned int u0 = *(const unsigned int*)(feat_bf + (size_t)s0 * 128 + lane * 2);
                unsigned int u1 = *(const unsigned int*)(feat_bf + (size_t)s1 * 128 + lane * 2);
                unsigned int u2 = *(const unsigned int*)(feat_bf + (size_t)s2 * 128 + lane * 2);
                unsigned int u3 = *(const unsigned int*)(feat_bf + (size_t)s3 * 128 + lane * 2);
                unsigned int u4 = *(const unsigned int*)(feat_bf + (size_t)s4 * 128 + lane * 2);
                unsigned int u5 = *(const unsigned int*)(feat_bf + (size_t)s5 * 128 + lane * 2);
                unsigned int u6 = *(const unsigned int*)(feat_bf + (size_t)s6 * 128 + lane * 2);
                unsigned int u7 = *(const unsigned int*)(feat_bf + (size_t)s7 * 128 + lane * 2);
                accx += (__uint_as_float(u0 << 16) + __uint_as_float(u1 << 16))
                      + (__uint_as_float(u2 << 16) + __uint_as_float(u3 << 16))
                      + (__uint_as_float(u4 << 16) + __uint_as_float(u5 << 16))
                      + (__uint_as_float(u6 << 16) + __uint_as_float(u7 << 16));
                accy += (__uint_as_float(u0 & 0xFFFF0000u) + __uint_as_float(u1 & 0xFFFF0000u))
                      + (__uint_as_float(u2 & 0xFFFF0000u) + __uint_as_float(u3 & 0xFFFF0000u))
                      + (__uint_as_float(u4 & 0xFFFF0000u) + __uint_as_float(u5 & 0xFFFF0000u))
                      + (__uint_as_float(u6 & 0xFFFF0000u) + __uint_as_float(u7 & 0xFFFF0000u));
            }
            for (; i + 3 < end; i += 4) {
                int s0 = src_sorted[i],     s1 = src_sorted[i + 1];
                int s2 = src_sorted[i + 2], s3 = src_sorted[i + 3];
                unsigned int u0 = *(const unsigned int*)(feat_bf + (size_t)s0 * 128 + lane * 2);
                unsigned int u1 = *(const unsigned int*)(feat_bf + (size_t)s1 * 128 + lane * 2);
                unsigned int u2 = *(const unsigned int*)(feat_bf + (size_t)s2 * 128 + lane * 2);
                unsigned int u3 = *(const unsigned int*)(feat_bf + (size_t)s3 * 128 + lane * 2);
                accx += __uint_as_float(u0 << 16) + __uint_as_float(u1 << 16)
                      + __uint_as_float(u2 << 16) + __uint_as_float(u3 << 16);
                accy += __uint_as_float(u0 & 0xFFFF0000u) + __uint_as_float(u1 & 0xFFFF0000u)
                      + __uint_as_float(u2 & 0xFFFF0000u) + __uint_as_float(u3 & 0xFFFF0000u);
            }
            for (; i < end; ++i) {
                unsigned int u = *(const unsigned int*)(feat_bf + (size_t)src_sorted[i] * 128 + lane * 2);
                accx += __uint_as_float(u << 16);
                accy += __uint_as_float(u & 0xFFFF0000u);
            }
        } else {
            for (; i + 3 < end; i += 4) {
                int s0 = src_sorted[i],     s1 = src_sorted[i + 1];
                int s2 = src_sorted[i + 2], s3 = src_sorted[i + 3];
                float2 v0 = ((const float2*)(feat_f32 + (size_t)s0 * 128))[lane];
                float2 v1 = ((const float2*)(feat_f32 + (size_t)s1 * 128))[lane];
                float2 v2 = ((const float2*)(feat_f32 + (size_t)s2 * 128))[lane];
                float2 v3 = ((const float2*)(feat_f32 + (size_t)s3 * 128))[lane];
                accx += (v0.x + v1.x) + (v2.x + v3.x);
                accy += (v0.y + v1.y) + (v2.y + v3.y);
            }
            for (; i < end; ++i) {
                float2 v = ((const float2*)(feat_f32 + (size_t)src_sorted[i] * 128))[lane];
                accx += v.x;
                accy += v.y;
            }
        }
    }
    unsigned int px = (unsigned int)f2bf_rne(accx);
    unsigned int py = (unsigned int)f2bf_rne(accy) << 16;
    *(unsigned int*)(htile + w * HT_STRIDE + lane * 2) = px | py;

    __syncthreads();

    if (w < 8) {
        int lane15 = lane & 15;
        int quad   = lane >> 4;

        float4v acc = {0.f, 0.f, 0.f, 0.f};
        #pragma unroll
        for (int kk = 0; kk < 4; kk++) {
            short8 afrag = *(const short8*)(htile + lane15 * HT_STRIDE + kk * 32 + quad * 8);
            short8 bfrag = *(const short8*)(w_bf + (size_t)(w * 16 + lane15) * 128 + kk * 32 + quad * 8);
            acc = __builtin_amdgcn_mfma_f32_16x16x32_bf16(afrag, bfrag, acc, 0, 0, 0);
        }
        float bv = bias[w * 16 + lane15];
        #pragma unroll
        for (int r = 0; r < 4; r++) {
            int row = node0 + quad * 4 + r;
            if (row < n_nodes)
                out[(size_t)row * 128 + w * 16 + lane15] = acc[r] + bv;
        }
    }
}

extern "C" void kernel_launch(void* const* d_in, const int* in_sizes, int n_in,
                              void* d_out, int out_size, void* d_ws, size_t ws_size,
                              hipStream_t stream) {
    const float* feature = (const float*)d_in[0];
    const int*   src     = (const int*)d_in[1];
    const int*   dst     = (const int*)d_in[2];
    const float* W       = (const float*)d_in[3];
    const float* b       = (const float*)d_in[4];

    const int D  = 128;
    int n_nodes  = in_sizes[0] / D;
    int n_edges  = in_sizes[1];
    int nb       = (n_nodes + 127) >> BKT_SHIFT;   // 391

    float* out = (float*)d_out;

    long nf = (long)n_nodes * D;      // feature elems (mult of 4)
    long nw = (long)D * D;            // W elems

    // ws: [feature_bf nf?] [w_bf nw] [pairs E int2] [src_sorted E] [offs N+1]
    //     [cnt128 512*128] [bucket_off 513]
    size_t tail_bytes = (size_t)n_edges * 8 + (size_t)n_edges * 4 +
                        (size_t)(n_nodes + 1) * 4 +
                        (size_t)(MAX_BKT * NPART + MAX_BKT + 1) * 4;
    size_t need_full  = (size_t)(nf + nw) * 2 + tail_bytes;
    int use_bf16 = (ws_size >= need_full) ? 1 : 0;   // constant across calls

    unsigned short* bf_base    = (unsigned short*)d_ws;
    long            nf_eff     = use_bf16 ? nf : 0;
    unsigned short* feature_bf = bf_base;            // valid only if use_bf16
    unsigned short* w_bf       = bf_base + nf_eff;
    int2* pairs        = (int2*)(bf_base + nf_eff + nw);
    int* src_sorted    = (int*)(pairs + n_edges);
    int* offs          = src_sorted + n_edges;
    int* cnt128        = offs + (n_nodes + 1);
    int* bucket_off    = cnt128 + MAX_BKT * NPART;

    int chunk = (n_edges + NPART - 1) / NPART;   // 6250

    // 1) conv + hist
    {
        long conv_blocks = ((nf_eff + nw) / 4 + 255) / 256;
        int grid = NPART + (int)conv_blocks;
        conv_hist_kernel<<<grid, 256, 0, stream>>>(
            feature, W, bf_base, nf_eff, nw, dst, cnt128, n_edges, nb, chunk);
    }

    // 2) redundant scan + scatter into bucket regions
    p_scatter_scan_kernel<<<NPART, 512, 0, stream>>>(
        src, dst, cnt128, pairs, bucket_off, n_edges, nb, chunk);

    // 3) per-bucket CSR
    local_csr_kernel<<<nb, 256, 0, stream>>>(pairs, bucket_off, offs, src_sorted,
                                             n_nodes, n_edges);

    // 4) fused gather (unroll-8) + MFMA projection
    {
        int blocks = (n_nodes + 15) / 16;   // 3125 blocks, 16 waves each
        gcn_gather_mm_kernel<<<blocks, 1024, 0, stream>>>(
            feature, feature_bf, use_bf16, offs, src_sorted, w_bf, b, out, n_nodes);
    }
}